// Round 6
// baseline (349.193 us; speedup 1.0000x reference)
//
#include <hip/hip_runtime.h>

#define MARGIN 0.2f
#define LAMBDA_CONSISTENCY 0.1f
#define COS_EPS 1e-8f

#define B_DIM 8192
#define NTHR  512
#define RPB   8
#define NBLK  (B_DIM / RPB)   // 1024 blocks, 2 per CU

// async global->LDS, 16B/lane. LDS dest = wave-uniform base + lane*16.
__device__ __forceinline__ void gload16(const float* g, float* l) {
  __builtin_amdgcn_global_load_lds(
      (const __attribute__((address_space(1))) void*)g,
      (__attribute__((address_space(3))) void*)l, 16, 0, 0);
}

// wave w (0..7) stages its 4KB slice of a 32KB row: 4 x gload16
__device__ __forceinline__ void stage_row(const float* rowg, float* buf,
                                          int w, int lane) {
#pragma unroll
  for (int j = 0; j < 4; ++j)
    gload16(rowg + w * 1024 + j * 256 + lane * 4, buf + w * 1024 + j * 256);
}

// ---------------------------------------------------------------------------
// Fused pass. 1024 blocks x 512 thr, 8 rows/block. LDS: K-row double buffer
// (64KB) + 0.5KB reduction area -> 2 blocks/CU (stagger covers stalls).
// Per-wave vmcnt queue per iter (order pinned by asm fences):
//   [H(kk) x4 (reg loads), stage(k+1) x4 (gload_lds)]
// - explicit vmcnt(8) certifies stage(k) done, leaves H+stage(k+1) in flight
// - compiler's auto-wait for H-use is vmcnt(4): stage(k+1) stays in flight
// Row d,s: wave shfl-reduce -> LDS partials -> plain stores at end (no
// mid-loop atomics so the static vmcnt counts stay exact).
// ---------------------------------------------------------------------------
__global__ __launch_bounds__(NTHR, 4) void fused_pass_kernel(
    const float* __restrict__ S, const int* __restrict__ ha,
    const int* __restrict__ ht,
    float* __restrict__ dot_col, float* __restrict__ colsq,
    float* __restrict__ dot_row, float* __restrict__ rowsq) {
  __shared__ __align__(16) float bufK[2][B_DIM];  // 64 KB
  __shared__ float redD[RPB * 8], redS[RPB * 8];
  const int t = threadIdx.x;
  const int w = t >> 6, lane = t & 63;

  // thread t owns cols 4t+2048q+c, q=0..3, c=0..3
  int hti[16];
#pragma unroll
  for (int q = 0; q < 4; ++q) {
    int4 h = ((const int4*)ht)[t + 512 * q];
    hti[4 * q + 0] = h.x; hti[4 * q + 1] = h.y;
    hti[4 * q + 2] = h.z; hti[4 * q + 3] = h.w;
  }

  float dacc[16], sacc[16];
#pragma unroll
  for (int c = 0; c < 16; ++c) { dacc[c] = 0.f; sacc[c] = 0.f; }

  const int k0 = blockIdx.x * RPB;

  // prologue: stage row k0 -> parity 0, drain, sync
  stage_row(S + (size_t)k0 * B_DIM, bufK[0], w, lane);
  int hak = ha[k0];
  asm volatile("s_waitcnt vmcnt(0)" ::: "memory");
  __builtin_amdgcn_s_barrier();
  asm volatile("" ::: "memory");

  for (int kk = 0; kk < RPB; ++kk) {
    const int k = k0 + kk;
    const int p = kk & 1;

    // H row (ha[k]) -> registers; issued FIRST in the vmcnt queue
    const float4* hrow4 = (const float4*)(S + (size_t)hak * B_DIM);
    float4 b0 = hrow4[t], b1 = hrow4[t + 512];
    float4 b2 = hrow4[t + 1024], b3 = hrow4[t + 1536];
    asm volatile("" ::: "memory");  // pin H loads before stage loads

    if (kk + 1 < RPB) {
      stage_row(S + (size_t)(k + 1) * B_DIM, bufK[p ^ 1], w, lane);
      hak = ha[k + 1];  // scalar (lgkm), doesn't touch vmcnt
      asm volatile("s_waitcnt vmcnt(8)" ::: "memory");  // stage(k) done
    } else {
      asm volatile("s_waitcnt vmcnt(4)" ::: "memory");  // stage(k) done
    }
    __builtin_amdgcn_s_barrier();   // whole row k staged by all waves
    asm volatile("" ::: "memory");

    const float4* bk4 = (const float4*)bufK[p];
    const float* bk = bufK[p];
    float4 v0 = bk4[t], v1 = bk4[t + 512];
    float4 v2 = bk4[t + 1024], v3 = bk4[t + 1536];
    const float vv[16] = {v0.x, v0.y, v0.z, v0.w, v1.x, v1.y, v1.z, v1.w,
                          v2.x, v2.y, v2.z, v2.w, v3.x, v3.y, v3.z, v3.w};
    const float bb[16] = {b0.x, b0.y, b0.z, b0.w, b1.x, b1.y, b1.z, b1.w,
                          b2.x, b2.y, b2.z, b2.w, b3.x, b3.y, b3.z, b3.w};

    float g[16];
#pragma unroll
    for (int c = 0; c < 16; ++c) g[c] = bk[hti[c]];  // random gather

    float d = 0.f, s = 0.f;
#pragma unroll
    for (int c = 0; c < 16; ++c) {
      dacc[c] += vv[c] * g[c];
      sacc[c] += vv[c] * vv[c];
      d += vv[c] * bb[c];   // H-use last: auto-wait vmcnt(4)
      s += vv[c] * vv[c];
    }
#pragma unroll
    for (int o = 32; o > 0; o >>= 1) {
      d += __shfl_down(d, o, 64);
      s += __shfl_down(s, o, 64);
    }
    if (lane == 0) { redD[kk * 8 + w] = d; redS[kk * 8 + w] = s; }

    asm volatile("" ::: "memory");
    __builtin_amdgcn_s_barrier();   // reuse guard for bufK[p]
  }

  __syncthreads();
  if (t < RPB) {   // plain stores, no atomics needed: block owns these rows
    float dd = 0.f, ss = 0.f;
#pragma unroll
    for (int w2 = 0; w2 < 8; ++w2) { dd += redD[t * 8 + w2]; ss += redS[t * 8 + w2]; }
    dot_row[k0 + t] = dd;
    rowsq[k0 + t] = ss;
  }

#pragma unroll
  for (int q = 0; q < 4; ++q)
#pragma unroll
    for (int c = 0; c < 4; ++c) {
      atomicAdd(&dot_col[4 * t + 2048 * q + c], dacc[4 * q + c]);
      atomicAdd(&colsq[4 * t + 2048 * q + c], sacc[4 * q + c]);
    }
}

// ---------------------------------------------------------------------------
// Finalize stage 1: 32 blocks x 256 thr, one i per thread. Scattered gathers
// are latency-hidden by 8192 parallel threads. Block partials -> 3 atomics.
// ---------------------------------------------------------------------------
__global__ __launch_bounds__(256) void finalize_partials(
    const float* __restrict__ S, const unsigned char* __restrict__ pmask,
    const int* __restrict__ ha, const int* __restrict__ ht,
    const float* __restrict__ dot_col, const float* __restrict__ colsq,
    const float* __restrict__ dot_row, const float* __restrict__ rowsq,
    float* __restrict__ scal) {
  const int t = threadIdx.x;
  const int i = blockIdx.x * 256 + t;

  const int a = ha[i];
  const int x = ht[i];
  const float m = pmask[(size_t)i * B_DIM + i] ? 1.f : 0.f;
  const float pos = S[(size_t)i * B_DIM + i];
  const float an  = S[(size_t)a * B_DIM + i];
  const float tn  = S[(size_t)i * B_DIM + x];

  float trip = fmaxf(MARGIN - pos + tn, 0.f) + fmaxf(MARGIN - pos + an, 0.f);
  const float cosA = dot_row[i] / fmaxf(sqrtf(rowsq[i]) * sqrtf(rowsq[a]), COS_EPS);
  const float cosT = dot_col[i] / fmaxf(sqrtf(colsq[i]) * sqrtf(colsq[x]), COS_EPS);
  float cons = fabsf(cosA - cosT);  // SIGMA_MARGIN = 0

  float cnt = m;
  trip *= m;
  cons *= m;

#pragma unroll
  for (int o = 32; o > 0; o >>= 1) {
    cnt  += __shfl_down(cnt, o, 64);
    trip += __shfl_down(trip, o, 64);
    cons += __shfl_down(cons, o, 64);
  }
  __shared__ float red[12];
  const int wid = t >> 6, lane = t & 63;
  if (lane == 0) { red[wid] = cnt; red[4 + wid] = trip; red[8 + wid] = cons; }
  __syncthreads();
  if (t == 0) {
    atomicAdd(&scal[0], red[0] + red[1] + red[2] + red[3]);
    atomicAdd(&scal[1], red[4] + red[5] + red[6] + red[7]);
    atomicAdd(&scal[2], red[8] + red[9] + red[10] + red[11]);
  }
}

// Finalize stage 2: assemble the 3 outputs.
__global__ void finalize_out(const float* __restrict__ scal,
                             float* __restrict__ out) {
  if (threadIdx.x == 0) {
    const float c = fmaxf(scal[0], 1.f);
    const float triplet = scal[1] / c;
    const float cons = scal[2] / c;
    out[0] = triplet + LAMBDA_CONSISTENCY * cons;
    out[1] = triplet;
    out[2] = cons;
  }
}

extern "C" void kernel_launch(void* const* d_in, const int* in_sizes, int n_in,
                              void* d_out, int out_size, void* d_ws, size_t ws_size,
                              hipStream_t stream) {
  const float* S = (const float*)d_in[0];
  const unsigned char* pmask = (const unsigned char*)d_in[1];  // jnp bool -> 1 byte
  const int* ha = (const int*)d_in[2];
  const int* ht = (const int*)d_in[3];

  float* ws = (float*)d_ws;
  float* dot_col = ws;
  float* colsq   = ws + B_DIM;
  float* dot_row = ws + 2 * B_DIM;
  float* rowsq   = ws + 3 * B_DIM;
  float* scal    = ws + 4 * B_DIM;   // [cnt, trip, cons]

  // zero dot_col, colsq (+ dot_row/rowsq harmlessly) and the 3 scalars
  hipMemsetAsync(ws, 0, (size_t)(4 * B_DIM + 4) * sizeof(float), stream);

  fused_pass_kernel<<<NBLK, NTHR, 0, stream>>>(
      S, ha, ht, dot_col, colsq, dot_row, rowsq);

  finalize_partials<<<B_DIM / 256, 256, 0, stream>>>(
      S, pmask, ha, ht, dot_col, colsq, dot_row, rowsq, scal);

  finalize_out<<<1, 64, 0, stream>>>(scal, (float*)d_out);
}

// Round 7
// 244.805 us; speedup vs baseline: 1.4264x; 1.4264x over previous
//
#include <hip/hip_runtime.h>

#define MARGIN 0.2f
#define LAMBDA_CONSISTENCY 0.1f
#define COS_EPS 1e-8f

#define B_DIM 8192
#define NTHR  1024
#define RPB   16
#define NBLK  (B_DIM / RPB)   // 512 blocks, 2 per CU (LDS 66KB)

// async global->LDS, 16B/lane. LDS dest = wave-uniform base + lane*16B.
__device__ __forceinline__ void gload16(const float* g, float* l) {
  __builtin_amdgcn_global_load_lds(
      (const __attribute__((address_space(1))) void*)g,
      (__attribute__((address_space(3))) void*)l, 16, 0, 0);
}

// wave w (0..15) stages its 2KB slice (512 floats) of a 32KB row: 2 ops
__device__ __forceinline__ void stage_row(const float* rowg, float* buf,
                                          int w, int lane) {
  gload16(rowg + 512 * w + 4 * lane,       buf + 512 * w);
  gload16(rowg + 512 * w + 256 + 4 * lane, buf + 512 * w + 256);
}

// ---------------------------------------------------------------------------
// Fused pass. 512 blocks x 1024 thr, 16 rows/block. LDS: K-row double buffer
// (64KB) + 2KB partials -> 2 blocks/CU. Per-thread live set ~60 VGPR
// (8 cols/thread) -- rounds 3/4/6 proved bigger sets spill; NO min-waves in
// launch_bounds (it halves the allocator's budget).
// Per-wave vmcnt queue per iter, order pinned by asm fences:
//   [stage(k) x2 (last iter), H(k) x2, stage(k+1) x2]
//  - explicit vmcnt(4): stage(k) done; H + stage(k+1) stay in flight
//  - compiler auto-wait for H-use: vmcnt(2); prefetch never drained
// Raw s_barrier (NOT __syncthreads: that emits vmcnt(0) and kills the
// pipeline). LDS reads are consumed before the end barrier, so buffer reuse
// is safe. No mid-loop atomics => static vmcnt counts stay exact.
// ---------------------------------------------------------------------------
__global__ __launch_bounds__(NTHR) void fused_pass_kernel(
    const float* __restrict__ S, const int* __restrict__ ha,
    const int* __restrict__ ht,
    float* __restrict__ dot_col, float* __restrict__ colsq,
    float* __restrict__ dot_row, float* __restrict__ rowsq) {
  __shared__ __align__(16) float bufK[2][B_DIM];   // 64 KB
  __shared__ float redD[RPB * 16], redS[RPB * 16]; // 2 KB
  const int t = threadIdx.x;
  const int w = t >> 6, lane = t & 63;

  // thread t owns cols 4t..4t+3 and 4096+4t..4096+4t+3
  int4 h0 = ((const int4*)ht)[t];
  int4 h1 = ((const int4*)ht)[t + 1024];
  const int hti[8] = {h0.x, h0.y, h0.z, h0.w, h1.x, h1.y, h1.z, h1.w};

  float dacc[8] = {0.f, 0.f, 0.f, 0.f, 0.f, 0.f, 0.f, 0.f};
  float sacc[8] = {0.f, 0.f, 0.f, 0.f, 0.f, 0.f, 0.f, 0.f};

  const int k0 = blockIdx.x * RPB;

  // prologue: stage row k0 -> parity 0, drain, sync
  stage_row(S + (size_t)k0 * B_DIM, bufK[0], w, lane);
  int hak = ha[k0];
  asm volatile("s_waitcnt vmcnt(0)" ::: "memory");
  __builtin_amdgcn_s_barrier();
  asm volatile("" ::: "memory");

  for (int kk = 0; kk < RPB; ++kk) {
    const int k = k0 + kk;
    const int p = kk & 1;

    // H row (ha[k]) -> 8 registers; FIRST in this iter's vmcnt queue
    const float4* hrow4 = (const float4*)(S + (size_t)hak * B_DIM);
    float4 b0 = hrow4[t], b1 = hrow4[t + 1024];
    asm volatile("" ::: "memory");  // pin H loads before stage DMA

    if (kk + 1 < RPB) {
      stage_row(S + (size_t)(k + 1) * B_DIM, bufK[p ^ 1], w, lane);
      hak = ha[k + 1];  // scalar path, doesn't touch vmcnt
      asm volatile("s_waitcnt vmcnt(4)" ::: "memory");  // stage(k) landed
    } else {
      asm volatile("s_waitcnt vmcnt(2)" ::: "memory");  // stage(k) landed
    }
    __builtin_amdgcn_s_barrier();   // whole row k visible to all waves
    asm volatile("" ::: "memory");

    const float* bk = bufK[p];
    const float4* bk4 = (const float4*)bk;
    float4 v0 = bk4[t], v1 = bk4[t + 1024];
    const float vv[8] = {v0.x, v0.y, v0.z, v0.w, v1.x, v1.y, v1.z, v1.w};
    const float bb[8] = {b0.x, b0.y, b0.z, b0.w, b1.x, b1.y, b1.z, b1.w};

    float g[8];
#pragma unroll
    for (int c = 0; c < 8; ++c) g[c] = bk[hti[c]];  // random gather ~2-way

    float d = 0.f, s = 0.f;
#pragma unroll
    for (int c = 0; c < 8; ++c) {
      dacc[c] += vv[c] * g[c];
      sacc[c] += vv[c] * vv[c];
      d += vv[c] * bb[c];           // H-use last: auto-wait vmcnt(2)
      s += vv[c] * vv[c];
    }
#pragma unroll
    for (int o = 32; o > 0; o >>= 1) {
      d += __shfl_down(d, o, 64);
      s += __shfl_down(s, o, 64);
    }
    if (lane == 0) { redD[kk * 16 + w] = d; redS[kk * 16 + w] = s; }

    asm volatile("" ::: "memory");
    __builtin_amdgcn_s_barrier();   // bufK[p] reuse guard (+ red visibility)
  }

  __syncthreads();
  if (t < RPB) {  // plain stores: block owns these rows
    float dd = 0.f, ss = 0.f;
#pragma unroll
    for (int w2 = 0; w2 < 16; ++w2) {
      dd += redD[t * 16 + w2];
      ss += redS[t * 16 + w2];
    }
    dot_row[k0 + t] = dd;
    rowsq[k0 + t] = ss;
  }

#pragma unroll
  for (int c = 0; c < 4; ++c) {
    atomicAdd(&dot_col[4 * t + c], dacc[c]);
    atomicAdd(&colsq[4 * t + c], sacc[c]);
    atomicAdd(&dot_col[4096 + 4 * t + c], dacc[4 + c]);
    atomicAdd(&colsq[4096 + 4 * t + c], sacc[4 + c]);
  }
}

// ---------------------------------------------------------------------------
// Finalize stage 1: 32 blocks x 256 thr, one i per thread. Scattered gathers
// latency-hidden by 8192 parallel threads. Block partials -> 3 atomics.
// ---------------------------------------------------------------------------
__global__ __launch_bounds__(256) void finalize_partials(
    const float* __restrict__ S, const unsigned char* __restrict__ pmask,
    const int* __restrict__ ha, const int* __restrict__ ht,
    const float* __restrict__ dot_col, const float* __restrict__ colsq,
    const float* __restrict__ dot_row, const float* __restrict__ rowsq,
    float* __restrict__ scal) {
  const int t = threadIdx.x;
  const int i = blockIdx.x * 256 + t;

  const int a = ha[i];
  const int x = ht[i];
  const float m = pmask[(size_t)i * B_DIM + i] ? 1.f : 0.f;
  const float pos = S[(size_t)i * B_DIM + i];
  const float an  = S[(size_t)a * B_DIM + i];
  const float tn  = S[(size_t)i * B_DIM + x];

  float trip = fmaxf(MARGIN - pos + tn, 0.f) + fmaxf(MARGIN - pos + an, 0.f);
  const float cosA = dot_row[i] / fmaxf(sqrtf(rowsq[i]) * sqrtf(rowsq[a]), COS_EPS);
  const float cosT = dot_col[i] / fmaxf(sqrtf(colsq[i]) * sqrtf(colsq[x]), COS_EPS);
  float cons = fabsf(cosA - cosT);  // SIGMA_MARGIN = 0

  float cnt = m;
  trip *= m;
  cons *= m;

#pragma unroll
  for (int o = 32; o > 0; o >>= 1) {
    cnt  += __shfl_down(cnt, o, 64);
    trip += __shfl_down(trip, o, 64);
    cons += __shfl_down(cons, o, 64);
  }
  __shared__ float red[12];
  const int wid = t >> 6, lane = t & 63;
  if (lane == 0) { red[wid] = cnt; red[4 + wid] = trip; red[8 + wid] = cons; }
  __syncthreads();
  if (t == 0) {
    atomicAdd(&scal[0], red[0] + red[1] + red[2] + red[3]);
    atomicAdd(&scal[1], red[4] + red[5] + red[6] + red[7]);
    atomicAdd(&scal[2], red[8] + red[9] + red[10] + red[11]);
  }
}

// Finalize stage 2: assemble the 3 outputs.
__global__ void finalize_out(const float* __restrict__ scal,
                             float* __restrict__ out) {
  if (threadIdx.x == 0) {
    const float c = fmaxf(scal[0], 1.f);
    const float triplet = scal[1] / c;
    const float cons = scal[2] / c;
    out[0] = triplet + LAMBDA_CONSISTENCY * cons;
    out[1] = triplet;
    out[2] = cons;
  }
}

extern "C" void kernel_launch(void* const* d_in, const int* in_sizes, int n_in,
                              void* d_out, int out_size, void* d_ws, size_t ws_size,
                              hipStream_t stream) {
  const float* S = (const float*)d_in[0];
  const unsigned char* pmask = (const unsigned char*)d_in[1];  // jnp bool -> 1B
  const int* ha = (const int*)d_in[2];
  const int* ht = (const int*)d_in[3];

  float* ws = (float*)d_ws;
  float* dot_col = ws;
  float* colsq   = ws + B_DIM;
  float* scal    = ws + 2 * B_DIM;         // [cnt, trip, cons, pad]
  float* dot_row = ws + 2 * B_DIM + 4;
  float* rowsq   = ws + 3 * B_DIM + 4;

  // zero the atomic accumulators (dot_col, colsq, scal) in one memset
  hipMemsetAsync(ws, 0, (size_t)(2 * B_DIM + 4) * sizeof(float), stream);

  fused_pass_kernel<<<NBLK, NTHR, 0, stream>>>(
      S, ha, ht, dot_col, colsq, dot_row, rowsq);

  finalize_partials<<<B_DIM / 256, 256, 0, stream>>>(
      S, pmask, ha, ht, dot_col, colsq, dot_row, rowsq, scal);

  finalize_out<<<1, 64, 0, stream>>>(scal, (float*)d_out);
}

// Round 8
// 223.239 us; speedup vs baseline: 1.5642x; 1.0966x over previous
//
#include <hip/hip_runtime.h>

#define MARGIN 0.2f
#define LAMBDA_CONSISTENCY 0.1f
#define COS_EPS 1e-8f

#define B_DIM 8192
#define NTHR  1024
#define RPB   16
#define NBLK  (B_DIM / RPB)   // 512 blocks, 2 per CU

// ---------------------------------------------------------------------------
// Fused pass — round-2 structure (the empirically fastest: compiler-scheduled
// plain loads + __syncthreads; every manual vmcnt/LDS-DMA variant was slower).
// Per row k: load row k -> regs (thread t owns cols 4t..4t+3, 4096+4t..+3),
// load row ha[k] -> regs, stage row k in LDS, sync, ht-gather from LDS +
// column accumulators from regs, row dot/norm -> wave partials in LDS, sync.
// Row outputs stored once at block end (no serial t0 chain inside the loop).
// __launch_bounds__(1024, 8): VGPR cap 64 -> 2 blocks/CU guaranteed; round 7
// proved this body fits (~40-56 live regs), so no spills (round 3's spill was
// a 3-row-pipeline live set, not this body).
// ---------------------------------------------------------------------------
__global__ __launch_bounds__(NTHR, 8) void fused_pass_kernel(
    const float* __restrict__ S, const int* __restrict__ ha,
    const int* __restrict__ ht,
    float* __restrict__ dot_col, float* __restrict__ colsq,
    float* __restrict__ dot_row, float* __restrict__ rowsq) {
  __shared__ __align__(16) float lds[B_DIM];       // 32 KB staging
  __shared__ float redD[RPB * 16], redS[RPB * 16]; // 2 KB wave partials
  float4* lds4 = (float4*)lds;
  const int t = threadIdx.x;
  const int w = t >> 6, lane = t & 63;

  int4 h0 = ((const int4*)ht)[t];
  int4 h1 = ((const int4*)ht)[t + 1024];
  const int hti[8] = {h0.x, h0.y, h0.z, h0.w, h1.x, h1.y, h1.z, h1.w};

  float dacc[8] = {0.f, 0.f, 0.f, 0.f, 0.f, 0.f, 0.f, 0.f};
  float sacc[8] = {0.f, 0.f, 0.f, 0.f, 0.f, 0.f, 0.f, 0.f};

  const int k0 = blockIdx.x * RPB;

  for (int kk = 0; kk < RPB; ++kk) {
    const int k = k0 + kk;
    const float4* rowk = (const float4*)(S + (size_t)k * B_DIM);
    const float4* rowa = (const float4*)(S + (size_t)ha[k] * B_DIM);
    float4 a0 = rowk[t], a1 = rowk[t + 1024];
    float4 b0 = rowa[t], b1 = rowa[t + 1024];
    lds4[t] = a0;
    lds4[t + 1024] = a1;

    float d = a0.x * b0.x + a0.y * b0.y + a0.z * b0.z + a0.w * b0.w
            + a1.x * b1.x + a1.y * b1.y + a1.z * b1.z + a1.w * b1.w;
    float s = a0.x * a0.x + a0.y * a0.y + a0.z * a0.z + a0.w * a0.w
            + a1.x * a1.x + a1.y * a1.y + a1.z * a1.z + a1.w * a1.w;

    __syncthreads();  // staged row visible

    const float vv[8] = {a0.x, a0.y, a0.z, a0.w, a1.x, a1.y, a1.z, a1.w};
    float g[8];
#pragma unroll
    for (int c = 0; c < 8; ++c) g[c] = lds[hti[c]];  // random gather, ~2-way
#pragma unroll
    for (int c = 0; c < 8; ++c) {
      dacc[c] += vv[c] * g[c];
      sacc[c] += vv[c] * vv[c];
    }

#pragma unroll
    for (int o = 32; o > 0; o >>= 1) {
      d += __shfl_down(d, o, 64);
      s += __shfl_down(s, o, 64);
    }
    if (lane == 0) { redD[kk * 16 + w] = d; redS[kk * 16 + w] = s; }

    __syncthreads();  // LDS reuse guard (also covers redD/redS at end)
  }

  if (t < RPB) {  // block owns these rows: plain stores
    float dd = 0.f, ss = 0.f;
#pragma unroll
    for (int w2 = 0; w2 < 16; ++w2) {
      dd += redD[t * 16 + w2];
      ss += redS[t * 16 + w2];
    }
    dot_row[k0 + t] = dd;
    rowsq[k0 + t] = ss;
  }

#pragma unroll
  for (int c = 0; c < 4; ++c) {
    atomicAdd(&dot_col[4 * t + c], dacc[c]);
    atomicAdd(&colsq[4 * t + c], sacc[c]);
    atomicAdd(&dot_col[4096 + 4 * t + c], dacc[4 + c]);
    atomicAdd(&colsq[4096 + 4 * t + c], sacc[4 + c]);
  }
}

// ---------------------------------------------------------------------------
// Finalize stage 1: 32 blocks x 256 thr, one i per thread. Scattered gathers
// latency-hidden by 8192 parallel threads. Block partials -> 3 atomics.
// ---------------------------------------------------------------------------
__global__ __launch_bounds__(256) void finalize_partials(
    const float* __restrict__ S, const unsigned char* __restrict__ pmask,
    const int* __restrict__ ha, const int* __restrict__ ht,
    const float* __restrict__ dot_col, const float* __restrict__ colsq,
    const float* __restrict__ dot_row, const float* __restrict__ rowsq,
    float* __restrict__ scal) {
  const int t = threadIdx.x;
  const int i = blockIdx.x * 256 + t;

  const int a = ha[i];
  const int x = ht[i];
  const float m = pmask[(size_t)i * B_DIM + i] ? 1.f : 0.f;
  const float pos = S[(size_t)i * B_DIM + i];
  const float an  = S[(size_t)a * B_DIM + i];
  const float tn  = S[(size_t)i * B_DIM + x];

  float trip = fmaxf(MARGIN - pos + tn, 0.f) + fmaxf(MARGIN - pos + an, 0.f);
  const float cosA = dot_row[i] / fmaxf(sqrtf(rowsq[i]) * sqrtf(rowsq[a]), COS_EPS);
  const float cosT = dot_col[i] / fmaxf(sqrtf(colsq[i]) * sqrtf(colsq[x]), COS_EPS);
  float cons = fabsf(cosA - cosT);  // SIGMA_MARGIN = 0

  float cnt = m;
  trip *= m;
  cons *= m;

#pragma unroll
  for (int o = 32; o > 0; o >>= 1) {
    cnt  += __shfl_down(cnt, o, 64);
    trip += __shfl_down(trip, o, 64);
    cons += __shfl_down(cons, o, 64);
  }
  __shared__ float red[12];
  const int wid = t >> 6, lane = t & 63;
  if (lane == 0) { red[wid] = cnt; red[4 + wid] = trip; red[8 + wid] = cons; }
  __syncthreads();
  if (t == 0) {
    atomicAdd(&scal[0], red[0] + red[1] + red[2] + red[3]);
    atomicAdd(&scal[1], red[4] + red[5] + red[6] + red[7]);
    atomicAdd(&scal[2], red[8] + red[9] + red[10] + red[11]);
  }
}

// Finalize stage 2: assemble the 3 outputs.
__global__ void finalize_out(const float* __restrict__ scal,
                             float* __restrict__ out) {
  if (threadIdx.x == 0) {
    const float c = fmaxf(scal[0], 1.f);
    const float triplet = scal[1] / c;
    const float cons = scal[2] / c;
    out[0] = triplet + LAMBDA_CONSISTENCY * cons;
    out[1] = triplet;
    out[2] = cons;
  }
}

extern "C" void kernel_launch(void* const* d_in, const int* in_sizes, int n_in,
                              void* d_out, int out_size, void* d_ws, size_t ws_size,
                              hipStream_t stream) {
  const float* S = (const float*)d_in[0];
  const unsigned char* pmask = (const unsigned char*)d_in[1];  // jnp bool -> 1B
  const int* ha = (const int*)d_in[2];
  const int* ht = (const int*)d_in[3];

  float* ws = (float*)d_ws;
  float* dot_col = ws;
  float* colsq   = ws + B_DIM;
  float* scal    = ws + 2 * B_DIM;         // [cnt, trip, cons, pad]
  float* dot_row = ws + 2 * B_DIM + 4;
  float* rowsq   = ws + 3 * B_DIM + 4;

  // zero the atomic accumulators (dot_col, colsq, scal) in one memset
  hipMemsetAsync(ws, 0, (size_t)(2 * B_DIM + 4) * sizeof(float), stream);

  fused_pass_kernel<<<NBLK, NTHR, 0, stream>>>(
      S, ha, ht, dot_col, colsq, dot_row, rowsq);

  finalize_partials<<<B_DIM / 256, 256, 0, stream>>>(
      S, pmask, ha, ht, dot_col, colsq, dot_row, rowsq, scal);

  finalize_out<<<1, 64, 0, stream>>>(scal, (float*)d_out);
}